// Round 2
// baseline (57.640 us; speedup 1.0000x reference)
//
#include <hip/hip_runtime.h>
#include <math.h>

#define IMG_H 2048
#define IMG_W 2048
#define NIMG 8

__device__ __forceinline__ float max3f(float a, float b, float c) {
    return fmaxf(fmaxf(a, b), c);
}
__device__ __forceinline__ float min3f(float a, float b, float c) {
    return fminf(fminf(a, b), c);
}

// fast sigmoid: ~1e-7 abs error (hw exp + IEEE div). Only used away from the
// decision boundary; borderline pixels fall through to the exact-emulation path.
__device__ __forceinline__ float fast_sigmoid(float v) {
    float e = __expf(-v);
    return 1.0f / (1.0f + e);
}

// Emulate numpy float32 pipeline: sigma = 1.0f / (1.0f + exp_f32(-x))
// with a correctly-rounded float32 exp (via double exp, then round to f32),
// keeping BOTH intermediate roundings (the f32 add and the f32 CR divide).
__device__ __forceinline__ float np_sigmoid_f32(float v) {
    float e = (float)exp(-(double)v);   // CR float32 exp
    float d = 1.0f + e;                 // f32 add (CR)
    return 1.0f / d;                    // f32 div (CR, no fast-math)
}

// Each thread: 4 output cols (float4-aligned) x 4 output rows.
// Block: 64 x 4 threads -> tile of 256 cols x 16 rows.
__global__ __launch_bounds__(256) void morph_grad_kernel(
    const float* __restrict__ in, float* __restrict__ out) {

    const int tx   = threadIdx.x;                  // 0..63
    const int ty   = threadIdx.y;                  // 0..3
    const int c    = blockIdx.x * 256 + tx * 4;    // output col base (mult of 4)
    const int row0 = blockIdx.y * 16 + ty * 4;     // output row base
    const int img  = blockIdx.z;

    const float* base = in + (size_t)img * IMG_H * IMG_W;

    // hM/hm: horizontal max/min over 5-wide window per row; cc: center value
    float hM[8][4], hm[8][4], cc[8][4];

    const bool hasL = (c != 0);          // c==0 is the only thread missing left halo
    const bool hasR = (c != IMG_W - 4);  // c==2044 is the only one missing right halo

    #pragma unroll
    for (int r = 0; r < 8; ++r) {
        int y = row0 - 2 + r;
        y = y < 0 ? 0 : (y > IMG_H - 1 ? IMG_H - 1 : y);   // clamp == geodesic here
        const float* rp = base + (size_t)y * IMG_W;

        float4 Mv = *reinterpret_cast<const float4*>(rp + c);       // 16B aligned
        float2 Lv, Rv;
        if (hasL) Lv = *reinterpret_cast<const float2*>(rp + c - 2); // 8B aligned
        else      Lv = make_float2(Mv.x, Mv.x);                      // clamp col
        if (hasR) Rv = *reinterpret_cast<const float2*>(rp + c + 4); // 16B aligned
        else      Rv = make_float2(Mv.w, Mv.w);                      // clamp col

        float w[8] = {Lv.x, Lv.y, Mv.x, Mv.y, Mv.z, Mv.w, Rv.x, Rv.y};
        #pragma unroll
        for (int j = 0; j < 4; ++j) {
            float t = max3f(w[j + 1], w[j + 2], w[j + 3]);
            hM[r][j] = max3f(w[j], w[j + 4], t);
            float u = min3f(w[j + 1], w[j + 2], w[j + 3]);
            hm[r][j] = min3f(w[j], w[j + 4], u);
            cc[r][j] = w[j + 2];
        }
    }

    float* obase = out + (size_t)img * IMG_H * IMG_W;

    #pragma unroll
    for (int k = 0; k < 4; ++k) {
        const int yo = row0 + k;
        float rr[4];
        #pragma unroll
        for (int j = 0; j < 4; ++j) {
            // rows yo-1..yo+1 fully covered by hM; rows yo+-2 only center col
            float Mv = max3f(hM[k + 1][j], hM[k + 2][j], hM[k + 3][j]);
            Mv = max3f(Mv, cc[k][j], cc[k + 4][j]);
            float mv = min3f(hm[k + 1][j], hm[k + 2][j], hm[k + 3][j]);
            mv = min3f(mv, cc[k][j], cc[k + 4][j]);

            float g = fast_sigmoid(Mv) - fast_sigmoid(mv);
            float res;
            if (__builtin_expect(fabsf(g - 0.5f) < 1e-4f, 0)) {
                // borderline: exact emulation of the np float32 pipeline
                float sM = np_sigmoid_f32(Mv);
                float sm = np_sigmoid_f32(mv);
                res = ((sM - sm) > 0.5f) ? 1.0f : 0.0f;
            } else {
                res = (g > 0.5f) ? 1.0f : 0.0f;
            }
            rr[j] = res;
        }
        float4 o = make_float4(rr[0], rr[1], rr[2], rr[3]);
        *reinterpret_cast<float4*>(obase + (size_t)yo * IMG_W + c) = o;  // 16B aligned
    }
}

extern "C" void kernel_launch(void* const* d_in, const int* in_sizes, int n_in,
                              void* d_out, int out_size, void* d_ws, size_t ws_size,
                              hipStream_t stream) {
    const float* x = (const float*)d_in[0];
    float* out = (float*)d_out;
    dim3 grid(IMG_W / 256, IMG_H / 16, NIMG);   // 8 x 128 x 8 = 8192 blocks
    dim3 block(64, 4, 1);
    hipLaunchKernelGGL(morph_grad_kernel, grid, block, 0, stream, x, out);
}